// Round 9
// baseline (171.290 us; speedup 1.0000x reference)
//
#include <hip/hip_runtime.h>

#define DEVI __device__ __forceinline__

typedef __bf16 bf16x8 __attribute__((ext_vector_type(8)));
typedef float f32x4 __attribute__((ext_vector_type(4)));

// B=4, C=256, H=W=48 -> N=2304, heads=8, hd=32
// fold 1/sqrt(32) * log2(e) into q so MFMA scores are already in exp2 domain
#define QSCALE 0.25503488f

#if __has_builtin(__builtin_amdgcn_exp2f)
#define EXP2(x) __builtin_amdgcn_exp2f(x)
#else
#define EXP2(x) __expf(0.69314718055994531f * (x))
#endif

DEVI unsigned short bfbits(float f) {
  union { __bf16 h; unsigned short u; } x;
  x.h = (__bf16)f;
  return x.u;
}
DEVI unsigned packbf2(float a, float b) {
  return (unsigned)bfbits(a) | ((unsigned)bfbits(b) << 16);
}
DEVI float bflo(unsigned u) { return __uint_as_float(u << 16); }
DEVI float bfhi(unsigned u) { return __uint_as_float(u & 0xffff0000u); }

DEVI void gload16(const unsigned short* g, void* l) {
  __builtin_amdgcn_global_load_lds((__attribute__((address_space(1))) const unsigned*)g,
                                   (__attribute__((address_space(3))) unsigned*)l, 16, 0, 0);
}

// ---------- K0a: x [B,C,N] f32 -> xT [B*N, C] bf16 (LDS-tiled transpose) ----------
__global__ __launch_bounds__(256) void k_prep_x(const float* __restrict__ x,
                                                unsigned short* __restrict__ xT) {
  __shared__ float tile[64][65];
  const int b = blockIdx.x, n0 = blockIdx.y * 64, c0 = blockIdx.z * 64;
  const int t = threadIdx.x, tn = t & 63, tg = t >> 6;
  const float* xp = x + ((size_t)b * 256 + c0) * 2304 + n0;
#pragma unroll
  for (int i = 0; i < 16; ++i) {
    const int c = tg * 16 + i;
    tile[c][tn] = xp[(size_t)c * 2304 + tn];
  }
  __syncthreads();
  unsigned short* op = xT + ((size_t)b * 2304 + n0) * 256 + c0;
#pragma unroll
  for (int i = 0; i < 16; ++i) {
    const int n = tg * 16 + i;
    op[(size_t)n * 256 + tn] = bfbits(tile[tn][n]);
  }
}

// ---------- K0b: Wo f32 -> bf16 (launched late, into dead qhm region) ----------
__global__ __launch_bounds__(256) void k_prep_wo(const float* __restrict__ Wo,
                                                 unsigned short* __restrict__ WoB) {
  const int i = (blockIdx.x * 256 + threadIdx.x) * 4;
  const float4 v = *(const float4*)(Wo + i);
  uint2 u;
  u.x = packbf2(v.x, v.y);
  u.y = packbf2(v.z, v.w);
  *(uint2*)(WoB + i) = u;
}

// ---------- K1: fused q+k projection -> HEAD-MAJOR [b*8+h][2304][32] bf16 ----------
// grid (144, 8): x = 64-row n-block (wave = 16n), y = head. Both matrices share
// the same xT A-fragments (halves scattered xT reads). W staged f32->bf16 in
// XOR-swizzled LDS.
__global__ __launch_bounds__(256) void k_proj_qk(const unsigned short* __restrict__ xT,
                                                 const float* __restrict__ Wq,
                                                 const float* __restrict__ Wk,
                                                 unsigned short* __restrict__ qhm,
                                                 unsigned short* __restrict__ khm) {
  __shared__ __align__(16) unsigned char wlds[32768];  // [mat 2][row 32][512B swz]
  const int l = threadIdx.x & 63, w = threadIdx.x >> 6;
  const int lr = l & 15, lg = l >> 4;
  const int row0 = blockIdx.x * 64 + w * 16;  // global n index (b*2304+n)
  const int h = blockIdx.y;
  {
    const int t = threadIdx.x;
    const int mat = t >> 7;       // 0=q, 1=k
    const int t2 = t & 127;
    const int row = t2 >> 2;      // 0..31
    const int cj0 = (t2 & 3) * 8; // 8 chunks of 16B (8 bf16 each)
    const float* wp = (mat ? Wk : Wq) + (size_t)(h * 32 + row) * 256;
    unsigned char* ldst = wlds + mat * 16384 + row * 512;
#pragma unroll
    for (int i = 0; i < 8; ++i) {
      const int cj = cj0 + i;
      const float4 v0 = *(const float4*)(wp + cj * 8);
      const float4 v1 = *(const float4*)(wp + cj * 8 + 4);
      uint4 u;
      u.x = packbf2(v0.x, v0.y);
      u.y = packbf2(v0.z, v0.w);
      u.z = packbf2(v1.x, v1.y);
      u.w = packbf2(v1.z, v1.w);
      *(uint4*)(ldst + ((cj * 16) ^ ((row & 7) << 4))) = u;
    }
  }
  __syncthreads();

  f32x4 acc[2][2];  // [mat][ot]
#pragma unroll
  for (int i = 0; i < 2; ++i)
#pragma unroll
    for (int j = 0; j < 2; ++j) acc[i][j] = (f32x4){0.f, 0.f, 0.f, 0.f};
  for (int ks = 0; ks < 8; ++ks) {
    const int c = ks * 32 + lg * 8;
    const bf16x8 a = *(const bf16x8*)(xT + (size_t)(row0 + lr) * 256 + c);
    bf16x8 bfr[2][2];
#pragma unroll
    for (int ot = 0; ot < 2; ++ot) {
      const int brow = ot * 16 + lr;
      const unsigned off = (unsigned)(brow * 512) + (((unsigned)((ks * 4 + lg) * 16)) ^ ((brow & 7) << 4));
      bfr[0][ot] = *(const bf16x8*)(wlds + off);
      bfr[1][ot] = *(const bf16x8*)(wlds + 16384 + off);
    }
#pragma unroll
    for (int m = 0; m < 2; ++m)
#pragma unroll
      for (int ot = 0; ot < 2; ++ot)
        acc[m][ot] = __builtin_amdgcn_mfma_f32_16x16x32_bf16(a, bfr[m][ot], acc[m][ot], 0, 0, 0);
  }
  const int b = row0 / 2304;
  const int nloc = row0 - b * 2304;
  const size_t slab = (size_t)(b * 8 + h) * 2304;
#pragma unroll
  for (int m = 0; m < 2; ++m) {
    unsigned short* outp = m ? khm : qhm;
    const float scale = m ? 1.0f : QSCALE;
#pragma unroll
    for (int ot = 0; ot < 2; ++ot)
#pragma unroll
      for (int r = 0; r < 4; ++r) {
        const int n = nloc + lg * 4 + r;
        const int d = ot * 16 + lr;
        outp[(slab + n) * 32 + d] = bfbits(acc[m][ot][r] * scale);
      }
  }
}

// ---------- K1v: v projection -> [b][c][n] bf16 (c = h*32+d) ----------
// Wv row-block staged f32->bf16 in swizzled LDS (shared by all 4 waves).
__global__ __launch_bounds__(256) void k_proj_v(const unsigned short* __restrict__ xT,
                                                const float* __restrict__ Wv,
                                                unsigned short* __restrict__ vN) {
  __shared__ __align__(16) unsigned char wlds[32768];
  const int l = threadIdx.x & 63, w = threadIdx.x >> 6;
  const int lr = l & 15, lg = l >> 4;
  const int rowbase = blockIdx.x * 64;
  const int col0 = blockIdx.y * 32;  // b*2304+n
  {
    const int t = threadIdx.x;
    const int row = t >> 2;        // 0..63
    const int cj0 = (t & 3) * 8;   // 8 chunks of 16B
    const float* wp = Wv + (size_t)(rowbase + row) * 256;
    unsigned char* ldst = wlds + row * 512;
#pragma unroll
    for (int i = 0; i < 8; ++i) {
      const int cj = cj0 + i;
      const float4 v0 = *(const float4*)(wp + cj * 8);
      const float4 v1 = *(const float4*)(wp + cj * 8 + 4);
      uint4 u;
      u.x = packbf2(v0.x, v0.y);
      u.y = packbf2(v0.z, v0.w);
      u.z = packbf2(v1.x, v1.y);
      u.w = packbf2(v1.z, v1.w);
      *(uint4*)(ldst + ((cj * 16) ^ ((row & 7) << 4))) = u;
    }
  }
  __syncthreads();

  f32x4 acc[2];
  acc[0] = (f32x4){0.f, 0.f, 0.f, 0.f};
  acc[1] = (f32x4){0.f, 0.f, 0.f, 0.f};
  for (int ks = 0; ks < 8; ++ks) {
    const int c = ks * 32 + lg * 8;
    bf16x8 a, bfr[2];
    const int arow = w * 16 + lr;
    a = *(const bf16x8*)(wlds + arow * 512 + (((unsigned)((ks * 4 + lg) * 16)) ^ ((arow & 7) << 4)));
#pragma unroll
    for (int nt = 0; nt < 2; ++nt)
      bfr[nt] = *(const bf16x8*)(xT + (size_t)(col0 + nt * 16 + lr) * 256 + c);
#pragma unroll
    for (int nt = 0; nt < 2; ++nt)
      acc[nt] = __builtin_amdgcn_mfma_f32_16x16x32_bf16(a, bfr[nt], acc[nt], 0, 0, 0);
  }
  const int b = blockIdx.y / 72, nb = (blockIdx.y % 72) * 32;
#pragma unroll
  for (int nt = 0; nt < 2; ++nt)
#pragma unroll
    for (int r = 0; r < 4; ++r) {
      const int o = rowbase + w * 16 + lg * 4 + r;
      const int n = nb + nt * 16 + lr;
      vN[(size_t)b * 589824 + (size_t)o * 2304 + n] = bfbits(acc[nt][r]);
    }
}

// ---------- K2: flash attention, split-KV, head-major contiguous K staging ----------
// K tile (64j x 32d) is contiguous 4KB in khm; each wave stages 1KB lane-contiguous
// (8 lines vs 64 scattered). Source chunk pre-swizzled with involution c^=(c>>2)&3
// so LDS frag reads (XOR lg^(lr&3), lane-constant) are ~conflict-free.
template <bool DIRECT>
__global__ __launch_bounds__(256) void k_attn(const unsigned short* __restrict__ qhm,
                                              const unsigned short* __restrict__ khm,
                                              const unsigned short* __restrict__ vN,
                                              unsigned short* __restrict__ partO,
                                              float* __restrict__ partS,
                                              unsigned short* __restrict__ attT,
                                              int tpc) {
  __shared__ __align__(16) unsigned char sm[32768];  // [0,16K)=P (4K/wave), [16K,24K)=K dbuf, [24K,32K)=V dbuf
  const int l = threadIdx.x & 63, w = threadIdx.x >> 6;
  const int lr = l & 15, lg = l >> 4;
  const int bh = blockIdx.y, b = bh >> 3, h = bh & 7;
  const int i0 = blockIdx.x * 128 + w * 32;
  const int c = blockIdx.z, t0 = c * tpc;
  unsigned char* smw = sm + w * 4096;
  const size_t slab = (size_t)bh * 2304;

  bf16x8 qf[2];
  {
    const unsigned short* qbase = qhm + (slab + i0) * 32;
#pragma unroll
    for (int it = 0; it < 2; ++it)
      qf[it] = *(const bf16x8*)(qbase + (it * 16 + lr) * 32 + lg * 8);
  }

  bf16x8 ones;
#pragma unroll
  for (int e = 0; e < 8; ++e) ones[e] = (__bf16)1.0f;

  f32x4 oacc[2][2];
#pragma unroll
  for (int i = 0; i < 2; ++i)
#pragma unroll
    for (int j = 0; j < 2; ++j) oacc[i][j] = (f32x4){0.f, 0.f, 0.f, 0.f};
  f32x4 psum[2];
  psum[0] = (f32x4){0.f, 0.f, 0.f, 0.f};
  psum[1] = (f32x4){0.f, 0.f, 0.f, 0.f};

  // staging sources (per lane). K: contiguous tile, pre-swizzled chunk index.
  const unsigned short* kbase = khm + slab * 32 + (size_t)(64 * w + (l ^ ((l >> 2) & 3))) * 8;
  const int vks = w >> 1;
  const int vlg = (w * 2 + (l >> 5)) & 3;
  const unsigned short* vsrc = vN + (size_t)(b * 256 + h * 32 + (l & 31)) * 2304 + vks * 32 + vlg * 8;
  const int kdst = 16384 + w * 1024;  // + buf*4096
  const int vdst = 24576 + w * 1024;
  const int kxor = ((lg ^ (lr & 3)) << 4);

  // prologue: stage tile t0 into buf 0
  gload16(kbase + (size_t)t0 * 2048, sm + kdst);
  gload16(vsrc + t0 * 64, sm + vdst);
  __syncthreads();

  for (int tt = 0; tt < tpc; ++tt) {
    const int buf = tt & 1;
    if (tt < tpc - 1) {
      const int nbuf = (tt + 1) & 1;
      gload16(kbase + (size_t)(t0 + tt + 1) * 2048, sm + kdst + nbuf * 4096);
      gload16(vsrc + (t0 + tt + 1) * 64, sm + vdst + nbuf * 4096);
    }

    const unsigned char* kb = sm + 16384 + buf * 4096;
    const unsigned char* vb = sm + 24576 + buf * 4096;

    bf16x8 kf[4];
    {
      const unsigned char* kread = kb + lr * 64 + kxor;
#pragma unroll
      for (int jt = 0; jt < 4; ++jt)
        kf[jt] = *(const bf16x8*)(kread + jt * 1024);
    }

    f32x4 s[4][2];
    const f32x4 zf = (f32x4){0.f, 0.f, 0.f, 0.f};
#pragma unroll
    for (int jt = 0; jt < 4; ++jt)
#pragma unroll
      for (int it = 0; it < 2; ++it)
        s[jt][it] = __builtin_amdgcn_mfma_f32_16x16x32_bf16(kf[jt], qf[it], zf, 0, 0, 0);

#pragma unroll
    for (int it = 0; it < 2; ++it) {
      const int iloc = it * 16 + lr;
      const unsigned swz = (unsigned)((iloc & 7) << 4);
      unsigned char* prow = smw + iloc * 128;
#pragma unroll
      for (int jt = 0; jt < 4; ++jt) {
        const float p0 = EXP2(s[jt][it][0]);
        const float p1 = EXP2(s[jt][it][1]);
        const float p2 = EXP2(s[jt][it][2]);
        const float p3 = EXP2(s[jt][it][3]);
        const unsigned jb = (unsigned)(jt * 32 + lg * 8);
        uint2 u;
        u.x = packbf2(p0, p1);
        u.y = packbf2(p2, p3);
        *(uint2*)(prow + (jb ^ swz)) = u;  // swz never flips bit2 -> dwords adjacent
      }
    }

    bf16x8 vf[2][2], pf[2][2];
#pragma unroll
    for (int dt = 0; dt < 2; ++dt)
#pragma unroll
      for (int ks = 0; ks < 2; ++ks)
        vf[dt][ks] = *(const bf16x8*)(vb + ks * 2048 + lg * 512 + (dt * 16 + lr) * 16);
#pragma unroll
    for (int it = 0; it < 2; ++it) {
      const int iloc = it * 16 + lr;
      const unsigned swz = (unsigned)((iloc & 7) << 4);
#pragma unroll
      for (int ks = 0; ks < 2; ++ks)
        pf[it][ks] = *(const bf16x8*)(smw + iloc * 128 + ((unsigned)(ks * 64 + lg * 16) ^ swz));
    }
#pragma unroll
    for (int dt = 0; dt < 2; ++dt)
#pragma unroll
      for (int it = 0; it < 2; ++it) {
        oacc[dt][it] = __builtin_amdgcn_mfma_f32_16x16x32_bf16(vf[dt][0], pf[it][0], oacc[dt][it], 0, 0, 0);
        oacc[dt][it] = __builtin_amdgcn_mfma_f32_16x16x32_bf16(vf[dt][1], pf[it][1], oacc[dt][it], 0, 0, 0);
      }
#pragma unroll
    for (int it = 0; it < 2; ++it) {
      psum[it] = __builtin_amdgcn_mfma_f32_16x16x32_bf16(ones, pf[it][0], psum[it], 0, 0, 0);
      psum[it] = __builtin_amdgcn_mfma_f32_16x16x32_bf16(ones, pf[it][1], psum[it], 0, 0, 0);
    }
    __syncthreads();
  }

  if (DIRECT) {
    // normalize + transpose via LDS (stride 68B) + coalesced store to attT [b*n][256]
#pragma unroll
    for (int it = 0; it < 2; ++it) {
      const float inv = 1.0f / psum[it][0];
      const int iloc = it * 16 + lr;
      unsigned char* orow = smw + iloc * 68;
#pragma unroll
      for (int dt = 0; dt < 2; ++dt) {
        const int d = dt * 16 + lg * 4;
        *(unsigned*)(orow + d * 2) = packbf2(oacc[dt][it][0] * inv, oacc[dt][it][1] * inv);
        *(unsigned*)(orow + d * 2 + 4) = packbf2(oacc[dt][it][2] * inv, oacc[dt][it][3] * inv);
      }
    }
    __syncthreads();
    unsigned* attu = (unsigned*)attT;
#pragma unroll
    for (int it2 = 0; it2 < 8; ++it2) {
      const int lin = it2 * 64 + l;
      const int row = lin >> 4, k = lin & 15;
      const unsigned u = *(const unsigned*)(smw + row * 68 + k * 4);
      attu[(size_t)(b * 2304 + i0 + row) * 128 + h * 16 + k] = u;
    }
  } else {
    const size_t pbase = ((size_t)(c * 32 + bh) * 2304 + i0) * 32;
#pragma unroll
    for (int it = 0; it < 2; ++it)
#pragma unroll
      for (int dt = 0; dt < 2; ++dt) {
        const size_t addr = pbase + (size_t)(it * 16 + lr) * 32 + dt * 16 + lg * 4;
        uint2 u;
        u.x = packbf2(oacc[dt][it][0], oacc[dt][it][1]);
        u.y = packbf2(oacc[dt][it][2], oacc[dt][it][3]);
        *(uint2*)(partO + addr) = u;
      }
    if (lg == 0) {
      const size_t sbase = (size_t)(c * 32 + bh) * 2304 + i0;
      partS[sbase + lr] = psum[0][0];
      partS[sbase + 16 + lr] = psum[1][0];
    }
  }
}

// ---------- K3: out = LN(Wo @ att + x) * gamma + beta ----------
// COMBINE=true: B-staging sums split-KV partials inline (k_combine fused away,
// attT round-trip eliminated). COMBINE=false: stage from attT (DIRECT path).
template <bool COMBINE>
__global__ __launch_bounds__(256) void k_out_ln(const unsigned short* __restrict__ Wo,
                                                const unsigned short* __restrict__ attT,
                                                const unsigned short* __restrict__ partO,
                                                const float* __restrict__ partS,
                                                int nc,
                                                const float* __restrict__ x,
                                                const float* __restrict__ gamma,
                                                const float* __restrict__ beta,
                                                float* __restrict__ out) {
  __shared__ __align__(16) unsigned char alds[8192];
  __shared__ float wsum[4][16], wsq[4][16], smean[16], srstd[16];
  const int l = threadIdx.x & 63, w = threadIdx.x >> 6;
  const int lr = l & 15, lg = l >> 4;
  const int b = blockIdx.x / 144;
  const int n0 = (blockIdx.x % 144) * 16;
  const int row0 = w * 64;
  const size_t bn0 = (size_t)b * 2304 + n0;

  if (COMBINE) {
    const int t = threadIdx.x;
    const int row = t >> 4;        // 0..15 (local n)
    const int i = n0 + row;        // per-(b,h) row index
    const int cj0 = (t & 15) * 2;  // 2 chunks of 16B (8 c each)
#pragma unroll
    for (int ii = 0; ii < 2; ++ii) {
      const int cj = cj0 + ii;
      const int h = cj >> 2;
      const int d0 = (cj & 3) * 8;
      const int bh8 = b * 8 + h;
      float ssum = 0.f;
      float a0 = 0.f, a1 = 0.f, a2 = 0.f, a3 = 0.f, a4 = 0.f, a5 = 0.f, a6 = 0.f, a7 = 0.f;
      for (int cz = 0; cz < nc; ++cz) {
        const size_t rbase = (size_t)(cz * 32 + bh8) * 2304 + i;
        ssum += partS[rbase];
        const uint4 v = *(const uint4*)(partO + rbase * 32 + d0);
        a0 += bflo(v.x); a1 += bfhi(v.x);
        a2 += bflo(v.y); a3 += bfhi(v.y);
        a4 += bflo(v.z); a5 += bfhi(v.z);
        a6 += bflo(v.w); a7 += bfhi(v.w);
      }
      const float inv = 1.0f / ssum;
      uint4 u;
      u.x = packbf2(a0 * inv, a1 * inv);
      u.y = packbf2(a2 * inv, a3 * inv);
      u.z = packbf2(a4 * inv, a5 * inv);
      u.w = packbf2(a6 * inv, a7 * inv);
      *(uint4*)(alds + row * 512 + ((cj * 16) ^ ((row & 7) << 4))) = u;
    }
  } else {
    const int t = threadIdx.x;
    const int row = t >> 4;
    const int cj0 = (t & 15) * 2;
#pragma unroll
    for (int ii = 0; ii < 2; ++ii) {
      const int cj = cj0 + ii;
      const uint4 v = *(const uint4*)(attT + (bn0 + row) * 256 + cj * 8);
      *(uint4*)(alds + row * 512 + ((cj * 16) ^ ((row & 7) << 4))) = v;
    }
  }
  __syncthreads();

  f32x4 acc[4];
#pragma unroll
  for (int i = 0; i < 4; ++i) acc[i] = (f32x4){0.f, 0.f, 0.f, 0.f};
  for (int ks = 0; ks < 8; ++ks) {
    const int c = ks * 32 + lg * 8;
    bf16x8 a[4], bb;
#pragma unroll
    for (int rt = 0; rt < 4; ++rt)
      a[rt] = *(const bf16x8*)(Wo + (size_t)(row0 + rt * 16 + lr) * 256 + c);
    bb = *(const bf16x8*)(alds + lr * 512 + (((unsigned)((ks * 4 + lg) * 16)) ^ ((lr & 7) << 4)));
#pragma unroll
    for (int rt = 0; rt < 4; ++rt)
      acc[rt] = __builtin_amdgcn_mfma_f32_16x16x32_bf16(a[rt], bb, acc[rt], 0, 0, 0);
  }
  const float* xb = x + (size_t)b * 589824;
  float vals[4][4];
  float s0 = 0.f, q0 = 0.f;
#pragma unroll
  for (int rt = 0; rt < 4; ++rt)
#pragma unroll
    for (int r = 0; r < 4; ++r) {
      const int o = row0 + rt * 16 + lg * 4 + r;
      const int n = n0 + lr;
      const float vv = acc[rt][r] + xb[(size_t)o * 2304 + n];
      vals[rt][r] = vv;
      s0 += vv;
      q0 += vv * vv;
    }
  s0 += __shfl_xor(s0, 16); s0 += __shfl_xor(s0, 32);
  q0 += __shfl_xor(q0, 16); q0 += __shfl_xor(q0, 32);
  if (l < 16) {
    wsum[w][l] = s0;
    wsq[w][l] = q0;
  }
  __syncthreads();
  if (threadIdx.x < 16) {
    const int c16 = threadIdx.x;
    const float S = wsum[0][c16] + wsum[1][c16] + wsum[2][c16] + wsum[3][c16];
    const float Q = wsq[0][c16] + wsq[1][c16] + wsq[2][c16] + wsq[3][c16];
    const float mean = S * (1.0f / 256.0f);
    const float var = Q * (1.0f / 256.0f) - mean * mean;
    smean[c16] = mean;
    srstd[c16] = rsqrtf(var + 1e-5f);
  }
  __syncthreads();
  {
    const float mean = smean[lr];
    const float rstd = srstd[lr];
    const int n = n0 + lr;
#pragma unroll
    for (int rt = 0; rt < 4; ++rt)
#pragma unroll
      for (int r = 0; r < 4; ++r) {
        const int o = row0 + rt * 16 + lg * 4 + r;
        out[(size_t)b * 589824 + (size_t)o * 2304 + n] =
            (vals[rt][r] - mean) * rstd * gamma[o] + beta[o];
      }
  }
}

extern "C" void kernel_launch(void* const* d_in, const int* in_sizes, int n_in,
                              void* d_out, int out_size, void* d_ws, size_t ws_size,
                              hipStream_t stream) {
  (void)in_sizes; (void)n_in; (void)out_size;
  const float* x = (const float*)d_in[0];
  const float* Wq = (const float*)d_in[1];
  const float* Wk = (const float*)d_in[2];
  const float* Wv = (const float*)d_in[3];
  const float* Wo = (const float*)d_in[4];
  const float* gamma = (const float*)d_in[5];
  const float* beta = (const float*)d_in[6];
  float* out = (float*)d_out;
  char* ws = (char*)d_ws;
  // ws layout (bytes):
  //   attT 0..4.72M | qhm 4.72..9.44M | khm 9.44..14.16M | vN 14.16..18.87M |
  //   xT 18.87..23.59M ; partO/partS overlay xT region (xT dead after projs);
  //   WoB overlays qhm (dead after attn), written by k_prep_wo launched post-attn.
  unsigned short* attT = (unsigned short*)(ws);
  unsigned short* qhm = (unsigned short*)(ws + 4718592);
  unsigned short* khm = (unsigned short*)(ws + 9437184);
  unsigned short* vN = (unsigned short*)(ws + 14155776);
  unsigned short* xT = (unsigned short*)(ws + 18874368);
  unsigned short* WoB = qhm;  // reused after attn

  const size_t base = 18874368;
  const size_t chunk = 4718592 + 294912;
  const size_t need4 = base + 4 * chunk;  // ~38.9 MB
  const size_t need2 = base + 2 * chunk;  // ~28.9 MB
  const int nc = (ws_size >= need4) ? 4 : (ws_size >= need2) ? 2 : 1;
  unsigned short* partO = (unsigned short*)(ws + base);
  float* partS = (float*)(ws + base + (size_t)nc * 4718592);

  k_prep_x<<<dim3(4, 36, 4), 256, 0, stream>>>(x, xT);
  k_proj_qk<<<dim3(144, 8), 256, 0, stream>>>(xT, Wq, Wk, qhm, khm);
  k_proj_v<<<dim3(4, 288), 256, 0, stream>>>(xT, Wv, vN);
  if (nc > 1) {
    k_attn<false><<<dim3(18, 32, nc), 256, 0, stream>>>(qhm, khm, vN, partO, partS, attT, 36 / nc);
    k_prep_wo<<<dim3(64), 256, 0, stream>>>(Wo, WoB);
    k_out_ln<true><<<dim3(576), 256, 0, stream>>>(WoB, attT, partO, partS, nc, x, gamma, beta, out);
  } else {
    k_attn<true><<<dim3(18, 32, 1), 256, 0, stream>>>(qhm, khm, vN, attT, (float*)attT, attT, 36);
    k_prep_wo<<<dim3(64), 256, 0, stream>>>(Wo, WoB);
    k_out_ln<false><<<dim3(576), 256, 0, stream>>>(WoB, attT, partO, partS, 1, x, gamma, beta, out);
  }
}